// Round 4
// 2837.661 us; speedup vs baseline: 1.0072x; 1.0072x over previous
//
#include <hip/hip_runtime.h>
#include <hip/hip_bf16.h>
#include <math.h>

// SBERTa forward, MI355X gfx950.
// B=8 T=512 D=768 L=12 H=12 F=3072 K=2 DH=64, N_tok=4096.
// GEMMs: bf16 MFMA 16x16x32, NT layout, 128x128x32 tile, 4 waves, m97-style
// global_load_lds width-16 staging. Wo split-K=2, W2 split-K=4 (templated ln5).
// Attention: padded score LDS (pitch 516), softmax held in regs, P stored bf16
// in reused LDS, phase-3 fragments via ds_read_b128.

typedef __bf16 bf16;
typedef __attribute__((ext_vector_type(8))) __bf16 bf16x8;
typedef __attribute__((ext_vector_type(4))) __bf16 bf16x4;
typedef __attribute__((ext_vector_type(4))) float f32x4;

#define N_TOK 4096
#define D_SZ 768
#define F_SZ 3072
#define L_SZ 12
#define MN_SZ ((size_t)N_TOK * D_SZ)
#define SPITCH 516  // f32 score pitch (pad 4 -> 2-way bank alias only, free)
#define PPITCH 520  // bf16 P pitch (spreads ds_read_b128 across bank groups)

// async global->LDS, 16B per lane, wave-uniform LDS base + lane*16
__device__ __forceinline__ void async_ld16(const void* g, void* l) {
  __builtin_amdgcn_global_load_lds((const __attribute__((address_space(1))) void*)g,
                                   (__attribute__((address_space(3))) void*)l, 16, 0, 0);
}

// ---------------------------------------------------------------- reductions
__device__ inline void block_reduce2(float& a, float& b, int tid) {
  #pragma unroll
  for (int off = 32; off; off >>= 1) {
    a += __shfl_xor(a, off);
    b += __shfl_xor(b, off);
  }
  __shared__ float red[8];
  if ((tid & 63) == 0) { red[tid >> 6] = a; red[4 + (tid >> 6)] = b; }
  __syncthreads();
  a = red[0] + red[1] + red[2] + red[3];
  b = red[4] + red[5] + red[6] + red[7];
  __syncthreads();
}

// ---------------------------------------------------------------- converts
__global__ void __launch_bounds__(256) f2b_kernel(const float* __restrict__ src,
                                                  bf16* __restrict__ dst, int n4) {
  int i = blockIdx.x * 256 + threadIdx.x;
  if (i >= n4) return;
  float4 v = ((const float4*)src)[i];
  bf16x4 o; o.x = (bf16)v.x; o.y = (bf16)v.y; o.z = (bf16)v.z; o.w = (bf16)v.w;
  *(bf16x4*)(dst + (size_t)i * 4) = o;
}

// wqkv layout: per layer, rows 0..767 = Wq[l], 768..1535 = Wk[l], 1536.. = Wv[l]; ld=768
__global__ void __launch_bounds__(256) build_wqkv_kernel(const float* __restrict__ Wq,
    const float* __restrict__ Wk, const float* __restrict__ Wv, bf16* __restrict__ dst) {
  int i = blockIdx.x * 256 + threadIdx.x;
  const int per_layer = 2304 * 768;
  long idx = (long)i * 4;
  if (idx >= 12L * per_layer) return;
  int l = (int)(idx / per_layer);
  int rem = (int)(idx - (long)l * per_layer);
  int r = rem / 768;
  int c = rem - r * 768;
  const float* src;
  if (r < 768)       src = Wq + ((size_t)l * 768 + r) * 768 + c;
  else if (r < 1536) src = Wk + ((size_t)l * 768 + (r - 768)) * 768 + c;
  else               src = Wv + ((size_t)l * 768 + (r - 1536)) * 768 + c;
  float4 v = *(const float4*)src;
  bf16x4 o; o.x = (bf16)v.x; o.y = (bf16)v.y; o.z = (bf16)v.z; o.w = (bf16)v.w;
  *(bf16x4*)(dst + idx) = o;
}

// ---------------------------------------------------------------- embedding
__global__ void __launch_bounds__(256) embed_a_kernel(const int* __restrict__ ids,
    const float* __restrict__ tok, const float* __restrict__ pos,
    const float* __restrict__ proto, const float* __restrict__ log_tau,
    float* __restrict__ h_base, float* __restrict__ p_out) {
  int n = blockIdx.x;
  int t = n & 511;
  int tid = threadIdx.x;
  int id = ids[n];
  float d0 = 0.f, d1 = 0.f;
  #pragma unroll
  for (int jj = 0; jj < 3; jj++) {
    int j = tid + jj * 256;
    float v = tok[(size_t)id * 768 + j] + pos[(size_t)t * 768 + j];
    h_base[(size_t)n * 768 + j] = v;
    d0 += v * proto[j];
    d1 += v * proto[768 + j];
  }
  block_reduce2(d0, d1, tid);
  if (tid == 0) {
    float tau = fmaxf(__expf(log_tau[0]), 0.25f);
    float a = d0 / tau, bb = d1 / tau;
    float m = fmaxf(a, bb);
    float e0 = __expf(a - m), e1 = __expf(bb - m);
    float si = e0 + e1;
    p_out[n * 2] = e0 / si;
    p_out[n * 2 + 1] = e1 / si;
  }
}

__global__ void __launch_bounds__(256) embed_c_kernel(const float* __restrict__ h_base,
    const float* __restrict__ p, const float* __restrict__ lang, const float* __restrict__ sw,
    const float* __restrict__ lw, const float* __restrict__ lb,
    float* __restrict__ s_out, float* __restrict__ h_out, bf16* __restrict__ h_bf) {
  int n = blockIdx.x;
  int t = n & 511;
  int tid = threadIdx.x;
  float p0 = p[n * 2], p1 = p[n * 2 + 1];
  float sv = 0.f;
  if (t > 0) sv = 1.f - (p0 * p[(n - 1) * 2] + p1 * p[(n - 1) * 2 + 1]);
  if (tid == 0) s_out[n] = sv;
  float x[3]; float sum = 0.f, sq = 0.f;
  #pragma unroll
  for (int jj = 0; jj < 3; jj++) {
    int j = tid + jj * 256;
    float v = h_base[(size_t)n * 768 + j] + p0 * lang[j] + p1 * lang[768 + j] + sv * sw[j];
    x[jj] = v; sum += v; sq += v * v;
  }
  block_reduce2(sum, sq, tid);
  float mean = sum * (1.f / 768.f);
  float var = fmaxf(sq * (1.f / 768.f) - mean * mean, 0.f);
  float inv = rsqrtf(var + 1e-12f);
  #pragma unroll
  for (int jj = 0; jj < 3; jj++) {
    int j = tid + jj * 256;
    float o = (x[jj] - mean) * inv * lw[j] + lb[j];
    h_out[(size_t)n * 768 + j] = o;
    h_bf[(size_t)n * 768 + j] = (bf16)o;
  }
}

// ---------------------------------------------------------------- fused LN (residual + NZ partials)
// out = LN(x1 + sum_z t[z] + bias) * w + bv ; writes fp32 + bf16
template <int NZ>
__global__ void __launch_bounds__(256) ln5_kernel(const float* __restrict__ x1,
    const float* __restrict__ t, const float* __restrict__ bias,
    const float* __restrict__ w, const float* __restrict__ bv,
    float* __restrict__ out_f, bf16* __restrict__ out_b) {
  int n = blockIdx.x;
  int tid = threadIdx.x;
  float x[3]; float sum = 0.f, sq = 0.f;
  #pragma unroll
  for (int jj = 0; jj < 3; jj++) {
    int j = tid + jj * 256;
    size_t o = (size_t)n * 768 + j;
    float v = x1[o] + bias[j];
    #pragma unroll
    for (int z = 0; z < NZ; z++) v += t[o + (size_t)z * MN_SZ];
    x[jj] = v; sum += v; sq += v * v;
  }
  block_reduce2(sum, sq, tid);
  float mean = sum * (1.f / 768.f);
  float var = fmaxf(sq * (1.f / 768.f) - mean * mean, 0.f);
  float inv = rsqrtf(var + 1e-12f);
  #pragma unroll
  for (int jj = 0; jj < 3; jj++) {
    int j = tid + jj * 256;
    float o = (x[jj] - mean) * inv * w[j] + bv[j];
    out_f[(size_t)n * 768 + j] = o;
    out_b[(size_t)n * 768 + j] = (bf16)o;
  }
}

// ---------------------------------------------------------------- GEMM (NT)
// C[m,n] = sum_k A[m,k]*B[n,k].
// MODE 1: f32 out, split-K over blockIdx.z (gridDim.z pieces), out C + z*M*N.
// MODE 2: bias+gelu, bf16 out.
// MODE 3: QKV: cols <1536 -> bf16 C (ld 1536); cols >=1536 -> transposed into vt C2.
template <int MODE>
__global__ void __launch_bounds__(256) gemm_nt(const bf16* __restrict__ A,
    const bf16* __restrict__ B, void* __restrict__ C, bf16* __restrict__ C2,
    const float* __restrict__ bias, int M, int N, int K) {
  __shared__ bf16 As[128 * 32];
  __shared__ bf16 Bs[128 * 32];
  const int tid = threadIdx.x;
  const int lane = tid & 63;
  const int wave = tid >> 6;
  const int wm = wave >> 1, wn = wave & 1;
  const int m0 = blockIdx.x * 128, n0 = blockIdx.y * 128;
  const int fr = lane & 15, fq = lane >> 4;
  const int srow = wave * 16 + (lane >> 2);
  const int scol = (lane & 3) * 8;

  int kb = 0, ke = K;
  if (MODE == 1) { int ks = K / gridDim.z; kb = blockIdx.z * ks; ke = kb + ks; }

  f32x4 acc[4][4] = {};
  const bf16* Ap = A + (size_t)(m0 + srow) * K + scol;
  const bf16* Bp = B + (size_t)(n0 + srow) * K + scol;
  bf16* AsW = &As[wave * 512];
  bf16* BsW = &Bs[wave * 512];
  for (int k0 = kb; k0 < ke; k0 += 32) {
    async_ld16(Ap + k0, AsW);
    async_ld16(Ap + (size_t)64 * K + k0, AsW + 64 * 32);
    async_ld16(Bp + k0, BsW);
    async_ld16(Bp + (size_t)64 * K + k0, BsW + 64 * 32);
    __syncthreads();
    bf16x8 af[4], bfr[4];
    #pragma unroll
    for (int i = 0; i < 4; i++) af[i]  = *(const bf16x8*)&As[(wm * 64 + i * 16 + fr) * 32 + fq * 8];
    #pragma unroll
    for (int i = 0; i < 4; i++) bfr[i] = *(const bf16x8*)&Bs[(wn * 64 + i * 16 + fr) * 32 + fq * 8];
    #pragma unroll
    for (int i = 0; i < 4; i++)
      #pragma unroll
      for (int j = 0; j < 4; j++)
        acc[i][j] = __builtin_amdgcn_mfma_f32_16x16x32_bf16(af[i], bfr[j], acc[i][j], 0, 0, 0);
    __syncthreads();
  }

  const bool vregion = (MODE == 3) && (n0 >= 1536);
  float* Cz = (MODE == 1) ? ((float*)C + (size_t)blockIdx.z * M * N) : (float*)C;
  #pragma unroll
  for (int i = 0; i < 4; i++) {
    int row0 = m0 + wm * 64 + i * 16 + fq * 4;
    #pragma unroll
    for (int j = 0; j < 4; j++) {
      int col = n0 + wn * 64 + j * 16 + fr;
      if (MODE == 3 && vregion) {
        int vcol = col - 1536;
        int h = vcol >> 6, dh = vcol & 63;
        int b = row0 >> 9, t0 = row0 & 511;
        bf16x4 o;
        #pragma unroll
        for (int r = 0; r < 4; r++) o[r] = (bf16)acc[i][j][r];
        *(bf16x4*)&C2[((size_t)(b * 12 + h) * 64 + dh) * 512 + t0] = o;
      } else {
        #pragma unroll
        for (int r = 0; r < 4; r++) {
          float v = acc[i][j][r];
          if (MODE == 2) {
            v += bias[col];
            v = 0.5f * v * (1.f + erff(v * 0.70710678118654752f));
          }
          if (MODE == 1)      Cz[(size_t)(row0 + r) * N + col] = v;
          else if (MODE == 3) ((bf16*)C)[(size_t)(row0 + r) * 1536 + col] = (bf16)v;
          else                ((bf16*)C)[(size_t)(row0 + r) * N + col] = (bf16)v;
        }
      }
    }
  }
}

// ---------------------------------------------------------------- attention
// One block = (b, h, 32 q-rows). qkv ld = 1536 (Q cols 0..767, K cols 768..1535).
__global__ void __launch_bounds__(256) attn_kernel(const bf16* __restrict__ qkv,
    const bf16* __restrict__ vt, const float* __restrict__ p, const float* __restrict__ s,
    const int* __restrict__ mask, const float* __restrict__ compat,
    const float* __restrict__ gamma, int l, bf16* __restrict__ ctx) {
  __shared__ float scb[32 * SPITCH];  // 66048 B; reused as bf16[32*PPITCH] after softmax
  const int tid = threadIdx.x;
  const int lane = tid & 63;
  const int w = tid >> 6;
  const int fr = lane & 15, fq = lane >> 4;
  const int qc = blockIdx.x, h = blockIdx.y, b = blockIdx.z;
  const int i0 = qc * 32;
  const float* Cm = compat + (size_t)(l * 12 + h) * 4;  // 2x2 row-major [k][j]
  const float gl = gamma[l];

  // ---- phase 1: scores -> scb (fp32, pitch 516: fq aliasing is free 2-way)
  bf16x8 qf[2][2];
  #pragma unroll
  for (int mt = 0; mt < 2; mt++)
    #pragma unroll
    for (int kk = 0; kk < 2; kk++)
      qf[mt][kk] = *(const bf16x8*)&qkv[(size_t)(b * 512 + i0 + mt * 16 + fr) * 1536 + h * 64 + kk * 32 + fq * 8];
  for (int ntl = 0; ntl < 8; ++ntl) {
    int j0 = (w * 8 + ntl) * 16;
    bf16x8 kf0 = *(const bf16x8*)&qkv[(size_t)(b * 512 + j0 + fr) * 1536 + 768 + h * 64 + fq * 8];
    bf16x8 kf1 = *(const bf16x8*)&qkv[(size_t)(b * 512 + j0 + fr) * 1536 + 768 + h * 64 + 32 + fq * 8];
    #pragma unroll
    for (int mt = 0; mt < 2; mt++) {
      f32x4 acc = {};
      acc = __builtin_amdgcn_mfma_f32_16x16x32_bf16(qf[mt][0], kf0, acc, 0, 0, 0);
      acc = __builtin_amdgcn_mfma_f32_16x16x32_bf16(qf[mt][1], kf1, acc, 0, 0, 0);
      #pragma unroll
      for (int r = 0; r < 4; r++)
        scb[(mt * 16 + fq * 4 + r) * SPITCH + j0 + fr] = acc[r] * 0.125f;
    }
  }

  // per-lane column-bias cache (cols j = lane + jj*64), loaded once
  float pj0[8], pj1[8], basej[8];
  #pragma unroll
  for (int jj = 0; jj < 8; jj++) {
    int j = lane + jj * 64;
    pj0[jj] = p[(b * 512 + j) * 2];
    pj1[jj] = p[(b * 512 + j) * 2 + 1];
    basej[jj] = gl * s[b * 512 + j] + (1.f - (float)mask[b * 512 + j]) * -10000.f;
  }
  __syncthreads();

  // ---- phase 2: softmax rows held in registers (8 rows/wave, 8 cols/lane)
  float xs[8][8];
  #pragma unroll
  for (int il = 0; il < 8; ++il) {
    int i = w * 8 + il;
    int qi = i0 + i;
    float p0 = p[(b * 512 + qi) * 2], p1 = p[(b * 512 + qi) * 2 + 1];
    float cp0 = p0 * Cm[0] + p1 * Cm[2];
    float cp1 = p0 * Cm[1] + p1 * Cm[3];
    float mx = -3.0e38f;
    #pragma unroll
    for (int jj = 0; jj < 8; jj++) {
      float v = scb[i * SPITCH + lane + jj * 64] + cp0 * pj0[jj] + cp1 * pj1[jj] + basej[jj];
      xs[il][jj] = v; mx = fmaxf(mx, v);
    }
    #pragma unroll
    for (int off = 32; off; off >>= 1) mx = fmaxf(mx, __shfl_xor(mx, off));
    float sum = 0.f;
    #pragma unroll
    for (int jj = 0; jj < 8; jj++) { float e = __expf(xs[il][jj] - mx); xs[il][jj] = e; sum += e; }
    #pragma unroll
    for (int off = 32; off; off >>= 1) sum += __shfl_xor(sum, off);
    float inv = 1.f / sum;
    #pragma unroll
    for (int jj = 0; jj < 8; jj++) xs[il][jj] *= inv;
  }
  __syncthreads();  // all reads of scb(f32) done -> safe to overwrite as bf16

  bf16* pbf = (bf16*)scb;
  #pragma unroll
  for (int il = 0; il < 8; ++il)
    #pragma unroll
    for (int jj = 0; jj < 8; jj++)
      pbf[(w * 8 + il) * PPITCH + lane + jj * 64] = (bf16)xs[il][jj];
  __syncthreads();

  // ---- phase 3: ctx = P V, P fragments via ds_read_b128
  const int mt3 = w & 1;
  const int ntb = (w >> 1) * 2;
  f32x4 acc3[2] = {};
  for (int kt = 0; kt < 16; ++kt) {
    bf16x8 af = *(const bf16x8*)&pbf[(mt3 * 16 + fr) * PPITCH + kt * 32 + fq * 8];
    #pragma unroll
    for (int np = 0; np < 2; np++) {
      bf16x8 vf = *(const bf16x8*)&vt[(size_t)((b * 12 + h) * 64 + (ntb + np) * 16 + fr) * 512 + kt * 32 + fq * 8];
      acc3[np] = __builtin_amdgcn_mfma_f32_16x16x32_bf16(af, vf, acc3[np], 0, 0, 0);
    }
  }
  #pragma unroll
  for (int np = 0; np < 2; np++)
    #pragma unroll
    for (int r = 0; r < 4; r++)
      ctx[(size_t)(b * 512 + i0 + mt3 * 16 + fq * 4 + r) * 768 + h * 64 + (ntb + np) * 16 + fr] = (bf16)acc3[np][r];
}

// ---------------------------------------------------------------- launcher
extern "C" void kernel_launch(void* const* d_in, const int* in_sizes, int n_in,
                              void* d_out, int out_size, void* d_ws, size_t ws_size,
                              hipStream_t stream) {
  const int*   input_ids  = (const int*)d_in[0];
  const int*   attn_mask  = (const int*)d_in[1];
  const float* tok_emb    = (const float*)d_in[2];
  const float* pos_emb    = (const float*)d_in[3];
  const float* lang_emb   = (const float*)d_in[4];
  const float* switch_emb = (const float*)d_in[5];
  const float* prototypes = (const float*)d_in[6];
  const float* log_tau    = (const float*)d_in[7];
  const float* emb_ln_w   = (const float*)d_in[8];
  const float* emb_ln_b   = (const float*)d_in[9];
  const float* Wq   = (const float*)d_in[10];
  const float* Wk   = (const float*)d_in[11];
  const float* Wv   = (const float*)d_in[12];
  const float* Wo   = (const float*)d_in[13];
  const float* Wo_b = (const float*)d_in[14];
  const float* compat = (const float*)d_in[15];
  const float* gamma  = (const float*)d_in[16];
  const float* W1   = (const float*)d_in[17];
  const float* b1   = (const float*)d_in[18];
  const float* W2   = (const float*)d_in[19];
  const float* b2   = (const float*)d_in[20];
  const float* ln1_w = (const float*)d_in[21];
  const float* ln1_b = (const float*)d_in[22];
  const float* ln2_w = (const float*)d_in[23];
  const float* ln2_b = (const float*)d_in[24];

  char* wsp = (char*)d_ws;
  size_t off = 0;
  auto alloc = [&](size_t bytes) { void* pp = wsp + off; off += (bytes + 255) & ~(size_t)255; return pp; };
  float* h_f      = (float*)alloc(MN_SZ * 4);
  bf16*  h_bf     = (bf16*)alloc(MN_SZ * 2);
  float* h_mid    = (float*)alloc(MN_SZ * 4);
  bf16*  h_mid_bf = (bf16*)alloc(MN_SZ * 2);
  float* tmp      = (float*)alloc(MN_SZ * 4 * 4);   // split-K partials z=0..3
  float* h_base   = tmp + 3 * MN_SZ;                // dead after embedding; overlay
  float* p_buf    = (float*)alloc((size_t)N_TOK * 2 * 4);
  float* s_buf    = (float*)alloc((size_t)N_TOK * 4);
  bf16*  qkv      = (bf16*)alloc((size_t)N_TOK * 1536 * 2);
  bf16*  vt       = (bf16*)alloc(MN_SZ * 2);
  bf16*  ctx      = (bf16*)alloc(MN_SZ * 2);
  bf16*  a1       = (bf16*)alloc((size_t)N_TOK * F_SZ * 2);
  bf16*  wqkv_bf  = (bf16*)alloc((size_t)L_SZ * 2304 * 768 * 2);
  bf16*  wo_bf    = (bf16*)alloc((size_t)L_SZ * 768 * 768 * 2);
  bf16*  w1_bf    = (bf16*)alloc((size_t)L_SZ * 3072 * 768 * 2);
  bf16*  w2_bf    = (bf16*)alloc((size_t)L_SZ * 768 * 3072 * 2);
  (void)ws_size; (void)in_sizes; (void)n_in; (void)out_size;

  // weight conversion (every call; inputs restored each timed iteration)
  build_wqkv_kernel<<<(12 * 2304 * 768 / 4 + 255) / 256, 256, 0, stream>>>(Wq, Wk, Wv, wqkv_bf);
  f2b_kernel<<<(12 * 768 * 768 / 4 + 255) / 256, 256, 0, stream>>>(Wo, wo_bf, 12 * 768 * 768 / 4);
  f2b_kernel<<<(12 * 3072 * 768 / 4 + 255) / 256, 256, 0, stream>>>(W1, w1_bf, 12 * 3072 * 768 / 4);
  f2b_kernel<<<(12 * 768 * 3072 / 4 + 255) / 256, 256, 0, stream>>>(W2, w2_bf, 12 * 768 * 3072 / 4);

  // embedding stage
  embed_a_kernel<<<N_TOK, 256, 0, stream>>>(input_ids, tok_emb, pos_emb, prototypes, log_tau,
                                            h_base, p_buf);
  embed_c_kernel<<<N_TOK, 256, 0, stream>>>(h_base, p_buf, lang_emb, switch_emb, emb_ln_w,
                                            emb_ln_b, s_buf, h_f, h_bf);

  for (int l = 0; l < 12; ++l) {
    gemm_nt<3><<<dim3(32, 18), 256, 0, stream>>>(h_bf, wqkv_bf + (size_t)l * 2304 * 768, qkv,
                                                 vt, nullptr, N_TOK, 2304, 768);
    attn_kernel<<<dim3(16, 12, 8), 256, 0, stream>>>(qkv, vt, p_buf, s_buf, attn_mask,
                                                     compat, gamma, l, ctx);
    gemm_nt<1><<<dim3(32, 6, 2), 256, 0, stream>>>(ctx, wo_bf + (size_t)l * 768 * 768, tmp,
                                                   nullptr, nullptr, N_TOK, 768, 768);
    ln5_kernel<2><<<N_TOK, 256, 0, stream>>>(h_f, tmp, Wo_b + l * 768,
                                             ln1_w + l * 768, ln1_b + l * 768, h_mid, h_mid_bf);
    gemm_nt<2><<<dim3(32, 24), 256, 0, stream>>>(h_mid_bf, w1_bf + (size_t)l * 3072 * 768, a1,
                                                 nullptr, b1 + l * 3072, N_TOK, 3072, 768);
    gemm_nt<1><<<dim3(32, 6, 4), 256, 0, stream>>>(a1, w2_bf + (size_t)l * 768 * 3072, tmp,
                                                   nullptr, nullptr, N_TOK, 768, 3072);
    float* hdst = (l == 11) ? (float*)d_out : h_f;
    ln5_kernel<4><<<N_TOK, 256, 0, stream>>>(h_mid, tmp, b2 + l * 768,
                                             ln2_w + l * 768, ln2_b + l * 768, hdst, h_bf);
  }
}

// Round 5
// 2799.032 us; speedup vs baseline: 1.0211x; 1.0138x over previous
//
#include <hip/hip_runtime.h>
#include <hip/hip_bf16.h>
#include <math.h>

// SBERTa forward, MI355X gfx950.
// B=8 T=512 D=768 L=12 H=12 F=3072 K=2 DH=64, N_tok=4096.
// GEMMs: bf16 MFMA 16x16x32, NT layout, 128x128 tile, BK=64 K-steps
// (half the barrier drains of BK=32), 4 waves, global_load_lds width-16
// staging with XOR-preswizzled source + swizzled ds_read (byte ^= (row&7)<<4)
// so ds_read_b128 is <=2-way bank aliased (free). Wo split-K=2, W2 split-K=4.
// Attention: padded score LDS (pitch 516), softmax held in regs, P stored bf16
// in reused LDS, phase-3 fragments via ds_read_b128.

typedef __bf16 bf16;
typedef __attribute__((ext_vector_type(8))) __bf16 bf16x8;
typedef __attribute__((ext_vector_type(4))) __bf16 bf16x4;
typedef __attribute__((ext_vector_type(4))) float f32x4;

#define N_TOK 4096
#define D_SZ 768
#define F_SZ 3072
#define L_SZ 12
#define MN_SZ ((size_t)N_TOK * D_SZ)
#define SPITCH 516  // f32 score pitch (pad 4 -> 2-way bank alias only, free)
#define PPITCH 520  // bf16 P pitch (spreads ds_read_b128 across bank groups)

// async global->LDS, 16B per lane, wave-uniform LDS base + lane*16
__device__ __forceinline__ void async_ld16(const void* g, void* l) {
  __builtin_amdgcn_global_load_lds((const __attribute__((address_space(1))) void*)g,
                                   (__attribute__((address_space(3))) void*)l, 16, 0, 0);
}

// ---------------------------------------------------------------- reductions
__device__ inline void block_reduce2(float& a, float& b, int tid) {
  #pragma unroll
  for (int off = 32; off; off >>= 1) {
    a += __shfl_xor(a, off);
    b += __shfl_xor(b, off);
  }
  __shared__ float red[8];
  if ((tid & 63) == 0) { red[tid >> 6] = a; red[4 + (tid >> 6)] = b; }
  __syncthreads();
  a = red[0] + red[1] + red[2] + red[3];
  b = red[4] + red[5] + red[6] + red[7];
  __syncthreads();
}

// ---------------------------------------------------------------- converts
__global__ void __launch_bounds__(256) f2b_kernel(const float* __restrict__ src,
                                                  bf16* __restrict__ dst, int n4) {
  int i = blockIdx.x * 256 + threadIdx.x;
  if (i >= n4) return;
  float4 v = ((const float4*)src)[i];
  bf16x4 o; o.x = (bf16)v.x; o.y = (bf16)v.y; o.z = (bf16)v.z; o.w = (bf16)v.w;
  *(bf16x4*)(dst + (size_t)i * 4) = o;
}

// wqkv layout: per layer, rows 0..767 = Wq[l], 768..1535 = Wk[l], 1536.. = Wv[l]; ld=768
__global__ void __launch_bounds__(256) build_wqkv_kernel(const float* __restrict__ Wq,
    const float* __restrict__ Wk, const float* __restrict__ Wv, bf16* __restrict__ dst) {
  int i = blockIdx.x * 256 + threadIdx.x;
  const int per_layer = 2304 * 768;
  long idx = (long)i * 4;
  if (idx >= 12L * per_layer) return;
  int l = (int)(idx / per_layer);
  int rem = (int)(idx - (long)l * per_layer);
  int r = rem / 768;
  int c = rem - r * 768;
  const float* src;
  if (r < 768)       src = Wq + ((size_t)l * 768 + r) * 768 + c;
  else if (r < 1536) src = Wk + ((size_t)l * 768 + (r - 768)) * 768 + c;
  else               src = Wv + ((size_t)l * 768 + (r - 1536)) * 768 + c;
  float4 v = *(const float4*)src;
  bf16x4 o; o.x = (bf16)v.x; o.y = (bf16)v.y; o.z = (bf16)v.z; o.w = (bf16)v.w;
  *(bf16x4*)(dst + idx) = o;
}

// ---------------------------------------------------------------- embedding
__global__ void __launch_bounds__(256) embed_a_kernel(const int* __restrict__ ids,
    const float* __restrict__ tok, const float* __restrict__ pos,
    const float* __restrict__ proto, const float* __restrict__ log_tau,
    float* __restrict__ h_base, float* __restrict__ p_out) {
  int n = blockIdx.x;
  int t = n & 511;
  int tid = threadIdx.x;
  int id = ids[n];
  float d0 = 0.f, d1 = 0.f;
  #pragma unroll
  for (int jj = 0; jj < 3; jj++) {
    int j = tid + jj * 256;
    float v = tok[(size_t)id * 768 + j] + pos[(size_t)t * 768 + j];
    h_base[(size_t)n * 768 + j] = v;
    d0 += v * proto[j];
    d1 += v * proto[768 + j];
  }
  block_reduce2(d0, d1, tid);
  if (tid == 0) {
    float tau = fmaxf(__expf(log_tau[0]), 0.25f);
    float a = d0 / tau, bb = d1 / tau;
    float m = fmaxf(a, bb);
    float e0 = __expf(a - m), e1 = __expf(bb - m);
    float si = e0 + e1;
    p_out[n * 2] = e0 / si;
    p_out[n * 2 + 1] = e1 / si;
  }
}

__global__ void __launch_bounds__(256) embed_c_kernel(const float* __restrict__ h_base,
    const float* __restrict__ p, const float* __restrict__ lang, const float* __restrict__ sw,
    const float* __restrict__ lw, const float* __restrict__ lb,
    float* __restrict__ s_out, float* __restrict__ h_out, bf16* __restrict__ h_bf) {
  int n = blockIdx.x;
  int t = n & 511;
  int tid = threadIdx.x;
  float p0 = p[n * 2], p1 = p[n * 2 + 1];
  float sv = 0.f;
  if (t > 0) sv = 1.f - (p0 * p[(n - 1) * 2] + p1 * p[(n - 1) * 2 + 1]);
  if (tid == 0) s_out[n] = sv;
  float x[3]; float sum = 0.f, sq = 0.f;
  #pragma unroll
  for (int jj = 0; jj < 3; jj++) {
    int j = tid + jj * 256;
    float v = h_base[(size_t)n * 768 + j] + p0 * lang[j] + p1 * lang[768 + j] + sv * sw[j];
    x[jj] = v; sum += v; sq += v * v;
  }
  block_reduce2(sum, sq, tid);
  float mean = sum * (1.f / 768.f);
  float var = fmaxf(sq * (1.f / 768.f) - mean * mean, 0.f);
  float inv = rsqrtf(var + 1e-12f);
  #pragma unroll
  for (int jj = 0; jj < 3; jj++) {
    int j = tid + jj * 256;
    float o = (x[jj] - mean) * inv * lw[j] + lb[j];
    h_out[(size_t)n * 768 + j] = o;
    h_bf[(size_t)n * 768 + j] = (bf16)o;
  }
}

// ---------------------------------------------------------------- fused LN (residual + NZ partials)
// out = LN(x1 + sum_z t[z] + bias) * w + bv ; writes fp32 + bf16
template <int NZ>
__global__ void __launch_bounds__(256) ln5_kernel(const float* __restrict__ x1,
    const float* __restrict__ t, const float* __restrict__ bias,
    const float* __restrict__ w, const float* __restrict__ bv,
    float* __restrict__ out_f, bf16* __restrict__ out_b) {
  int n = blockIdx.x;
  int tid = threadIdx.x;
  float x[3]; float sum = 0.f, sq = 0.f;
  #pragma unroll
  for (int jj = 0; jj < 3; jj++) {
    int j = tid + jj * 256;
    size_t o = (size_t)n * 768 + j;
    float v = x1[o] + bias[j];
    #pragma unroll
    for (int z = 0; z < NZ; z++) v += t[o + (size_t)z * MN_SZ];
    x[jj] = v; sum += v; sq += v * v;
  }
  block_reduce2(sum, sq, tid);
  float mean = sum * (1.f / 768.f);
  float var = fmaxf(sq * (1.f / 768.f) - mean * mean, 0.f);
  float inv = rsqrtf(var + 1e-12f);
  #pragma unroll
  for (int jj = 0; jj < 3; jj++) {
    int j = tid + jj * 256;
    float o = (x[jj] - mean) * inv * w[j] + bv[j];
    out_f[(size_t)n * 768 + j] = o;
    out_b[(size_t)n * 768 + j] = (bf16)o;
  }
}

// ---------------------------------------------------------------- GEMM (NT)
// C[m,n] = sum_k A[m,k]*B[n,k].  BK=64 K-steps; LDS [128][64] bf16 per operand,
// XOR-swizzled: LDS row r chunk c (16B units) holds global chunk c^(r&7).
// Staging keeps LDS dest linear (global_load_lds requirement) and pre-swizzles
// the global source column; ds_read applies the same XOR -> <=2-way bank alias.
// MODE 1: f32 out, split-K over blockIdx.z (gridDim.z pieces), out C + z*M*N.
// MODE 2: bias+gelu, bf16 out.
// MODE 3: QKV: cols <1536 -> bf16 C (ld 1536); cols >=1536 -> transposed into vt C2.
template <int MODE>
__global__ void __launch_bounds__(256) gemm_nt(const bf16* __restrict__ A,
    const bf16* __restrict__ B, void* __restrict__ C, bf16* __restrict__ C2,
    const float* __restrict__ bias, int M, int N, int K) {
  __shared__ __align__(16) bf16 As[128 * 64];
  __shared__ __align__(16) bf16 Bs[128 * 64];
  const int tid = threadIdx.x;
  const int lane = tid & 63;
  const int wave = tid >> 6;
  const int wm = wave >> 1, wn = wave & 1;
  const int m0 = blockIdx.x * 128, n0 = blockIdx.y * 128;
  const int fr = lane & 15, fq = lane >> 4;
  const int lrow = lane >> 3;                 // 0..7 : row within 8-row stage chunk
  const int lcol = ((lane & 7) ^ lrow) << 3;  // pre-swizzled global col (elems)
  const int xsw = (fr & 7) << 4;              // byte XOR for swizzled ds_read

  int kb = 0, ke = K;
  if (MODE == 1) { int ks = K / gridDim.z; kb = blockIdx.z * ks; ke = kb + ks; }

  f32x4 acc[4][4] = {};
  // each wave stages rows {wave*8 + lrow + 32*c} for c=0..3 (8 rows / instr)
  const bf16* Ap = A + (size_t)(m0 + wave * 8 + lrow) * K + lcol;
  const bf16* Bp = B + (size_t)(n0 + wave * 8 + lrow) * K + lcol;
  bf16* AsW = &As[wave * 8 * 64];
  bf16* BsW = &Bs[wave * 8 * 64];
  for (int k0 = kb; k0 < ke; k0 += 64) {
    #pragma unroll
    for (int c = 0; c < 4; c++) {
      async_ld16(Ap + (size_t)(c * 32) * K + k0, AsW + c * 32 * 64);
      async_ld16(Bp + (size_t)(c * 32) * K + k0, BsW + c * 32 * 64);
    }
    __syncthreads();
    #pragma unroll
    for (int kk = 0; kk < 2; kk++) {
      bf16x8 af[4], bfr[4];
      #pragma unroll
      for (int i = 0; i < 4; i++)
        af[i] = *(const bf16x8*)((const char*)As +
                 (wm * 64 + i * 16 + fr) * 128 + ((kk * 64 + fq * 16) ^ xsw));
      #pragma unroll
      for (int i = 0; i < 4; i++)
        bfr[i] = *(const bf16x8*)((const char*)Bs +
                 (wn * 64 + i * 16 + fr) * 128 + ((kk * 64 + fq * 16) ^ xsw));
      #pragma unroll
      for (int i = 0; i < 4; i++)
        #pragma unroll
        for (int j = 0; j < 4; j++)
          acc[i][j] = __builtin_amdgcn_mfma_f32_16x16x32_bf16(af[i], bfr[j], acc[i][j], 0, 0, 0);
    }
    __syncthreads();
  }

  const bool vregion = (MODE == 3) && (n0 >= 1536);
  float* Cz = (MODE == 1) ? ((float*)C + (size_t)blockIdx.z * M * N) : (float*)C;
  #pragma unroll
  for (int i = 0; i < 4; i++) {
    int row0 = m0 + wm * 64 + i * 16 + fq * 4;
    #pragma unroll
    for (int j = 0; j < 4; j++) {
      int col = n0 + wn * 64 + j * 16 + fr;
      if (MODE == 3 && vregion) {
        int vcol = col - 1536;
        int h = vcol >> 6, dh = vcol & 63;
        int b = row0 >> 9, t0 = row0 & 511;
        bf16x4 o;
        #pragma unroll
        for (int r = 0; r < 4; r++) o[r] = (bf16)acc[i][j][r];
        *(bf16x4*)&C2[((size_t)(b * 12 + h) * 64 + dh) * 512 + t0] = o;
      } else {
        #pragma unroll
        for (int r = 0; r < 4; r++) {
          float v = acc[i][j][r];
          if (MODE == 2) {
            v += bias[col];
            v = 0.5f * v * (1.f + erff(v * 0.70710678118654752f));
          }
          if (MODE == 1)      Cz[(size_t)(row0 + r) * N + col] = v;
          else if (MODE == 3) ((bf16*)C)[(size_t)(row0 + r) * 1536 + col] = (bf16)v;
          else                ((bf16*)C)[(size_t)(row0 + r) * N + col] = (bf16)v;
        }
      }
    }
  }
}

// ---------------------------------------------------------------- attention
// One block = (b, h, 32 q-rows). qkv ld = 1536 (Q cols 0..767, K cols 768..1535).
__global__ void __launch_bounds__(256) attn_kernel(const bf16* __restrict__ qkv,
    const bf16* __restrict__ vt, const float* __restrict__ p, const float* __restrict__ s,
    const int* __restrict__ mask, const float* __restrict__ compat,
    const float* __restrict__ gamma, int l, bf16* __restrict__ ctx) {
  __shared__ float scb[32 * SPITCH];  // 66048 B; reused as bf16[32*PPITCH] after softmax
  const int tid = threadIdx.x;
  const int lane = tid & 63;
  const int w = tid >> 6;
  const int fr = lane & 15, fq = lane >> 4;
  const int qc = blockIdx.x, h = blockIdx.y, b = blockIdx.z;
  const int i0 = qc * 32;
  const float* Cm = compat + (size_t)(l * 12 + h) * 4;  // 2x2 row-major [k][j]
  const float gl = gamma[l];

  // ---- phase 1: scores -> scb (fp32, pitch 516: fq aliasing is free 2-way)
  bf16x8 qf[2][2];
  #pragma unroll
  for (int mt = 0; mt < 2; mt++)
    #pragma unroll
    for (int kk = 0; kk < 2; kk++)
      qf[mt][kk] = *(const bf16x8*)&qkv[(size_t)(b * 512 + i0 + mt * 16 + fr) * 1536 + h * 64 + kk * 32 + fq * 8];
  for (int ntl = 0; ntl < 8; ++ntl) {
    int j0 = (w * 8 + ntl) * 16;
    bf16x8 kf0 = *(const bf16x8*)&qkv[(size_t)(b * 512 + j0 + fr) * 1536 + 768 + h * 64 + fq * 8];
    bf16x8 kf1 = *(const bf16x8*)&qkv[(size_t)(b * 512 + j0 + fr) * 1536 + 768 + h * 64 + 32 + fq * 8];
    #pragma unroll
    for (int mt = 0; mt < 2; mt++) {
      f32x4 acc = {};
      acc = __builtin_amdgcn_mfma_f32_16x16x32_bf16(qf[mt][0], kf0, acc, 0, 0, 0);
      acc = __builtin_amdgcn_mfma_f32_16x16x32_bf16(qf[mt][1], kf1, acc, 0, 0, 0);
      #pragma unroll
      for (int r = 0; r < 4; r++)
        scb[(mt * 16 + fq * 4 + r) * SPITCH + j0 + fr] = acc[r] * 0.125f;
    }
  }

  // per-lane column-bias cache (cols j = lane + jj*64), loaded once
  float pj0[8], pj1[8], basej[8];
  #pragma unroll
  for (int jj = 0; jj < 8; jj++) {
    int j = lane + jj * 64;
    pj0[jj] = p[(b * 512 + j) * 2];
    pj1[jj] = p[(b * 512 + j) * 2 + 1];
    basej[jj] = gl * s[b * 512 + j] + (1.f - (float)mask[b * 512 + j]) * -10000.f;
  }
  __syncthreads();

  // ---- phase 2: softmax rows held in registers (8 rows/wave, 8 cols/lane)
  float xs[8][8];
  #pragma unroll
  for (int il = 0; il < 8; ++il) {
    int i = w * 8 + il;
    int qi = i0 + i;
    float p0 = p[(b * 512 + qi) * 2], p1 = p[(b * 512 + qi) * 2 + 1];
    float cp0 = p0 * Cm[0] + p1 * Cm[2];
    float cp1 = p0 * Cm[1] + p1 * Cm[3];
    float mx = -3.0e38f;
    #pragma unroll
    for (int jj = 0; jj < 8; jj++) {
      float v = scb[i * SPITCH + lane + jj * 64] + cp0 * pj0[jj] + cp1 * pj1[jj] + basej[jj];
      xs[il][jj] = v; mx = fmaxf(mx, v);
    }
    #pragma unroll
    for (int off = 32; off; off >>= 1) mx = fmaxf(mx, __shfl_xor(mx, off));
    float sum = 0.f;
    #pragma unroll
    for (int jj = 0; jj < 8; jj++) { float e = __expf(xs[il][jj] - mx); xs[il][jj] = e; sum += e; }
    #pragma unroll
    for (int off = 32; off; off >>= 1) sum += __shfl_xor(sum, off);
    float inv = 1.f / sum;
    #pragma unroll
    for (int jj = 0; jj < 8; jj++) xs[il][jj] *= inv;
  }
  __syncthreads();  // all reads of scb(f32) done -> safe to overwrite as bf16

  bf16* pbf = (bf16*)scb;
  #pragma unroll
  for (int il = 0; il < 8; ++il)
    #pragma unroll
    for (int jj = 0; jj < 8; jj++)
      pbf[(w * 8 + il) * PPITCH + lane + jj * 64] = (bf16)xs[il][jj];
  __syncthreads();

  // ---- phase 3: ctx = P V, P fragments via ds_read_b128
  const int mt3 = w & 1;
  const int ntb = (w >> 1) * 2;
  f32x4 acc3[2] = {};
  for (int kt = 0; kt < 16; ++kt) {
    bf16x8 af = *(const bf16x8*)&pbf[(mt3 * 16 + fr) * PPITCH + kt * 32 + fq * 8];
    #pragma unroll
    for (int np = 0; np < 2; np++) {
      bf16x8 vf = *(const bf16x8*)&vt[(size_t)((b * 12 + h) * 64 + (ntb + np) * 16 + fr) * 512 + kt * 32 + fq * 8];
      acc3[np] = __builtin_amdgcn_mfma_f32_16x16x32_bf16(af, vf, acc3[np], 0, 0, 0);
    }
  }
  #pragma unroll
  for (int np = 0; np < 2; np++)
    #pragma unroll
    for (int r = 0; r < 4; r++)
      ctx[(size_t)(b * 512 + i0 + mt3 * 16 + fq * 4 + r) * 768 + h * 64 + (ntb + np) * 16 + fr] = (bf16)acc3[np][r];
}

// ---------------------------------------------------------------- launcher
extern "C" void kernel_launch(void* const* d_in, const int* in_sizes, int n_in,
                              void* d_out, int out_size, void* d_ws, size_t ws_size,
                              hipStream_t stream) {
  const int*   input_ids  = (const int*)d_in[0];
  const int*   attn_mask  = (const int*)d_in[1];
  const float* tok_emb    = (const float*)d_in[2];
  const float* pos_emb    = (const float*)d_in[3];
  const float* lang_emb   = (const float*)d_in[4];
  const float* switch_emb = (const float*)d_in[5];
  const float* prototypes = (const float*)d_in[6];
  const float* log_tau    = (const float*)d_in[7];
  const float* emb_ln_w   = (const float*)d_in[8];
  const float* emb_ln_b   = (const float*)d_in[9];
  const float* Wq   = (const float*)d_in[10];
  const float* Wk   = (const float*)d_in[11];
  const float* Wv   = (const float*)d_in[12];
  const float* Wo   = (const float*)d_in[13];
  const float* Wo_b = (const float*)d_in[14];
  const float* compat = (const float*)d_in[15];
  const float* gamma  = (const float*)d_in[16];
  const float* W1   = (const float*)d_in[17];
  const float* b1   = (const float*)d_in[18];
  const float* W2   = (const float*)d_in[19];
  const float* b2   = (const float*)d_in[20];
  const float* ln1_w = (const float*)d_in[21];
  const float* ln1_b = (const float*)d_in[22];
  const float* ln2_w = (const float*)d_in[23];
  const float* ln2_b = (const float*)d_in[24];

  char* wsp = (char*)d_ws;
  size_t off = 0;
  auto alloc = [&](size_t bytes) { void* pp = wsp + off; off += (bytes + 255) & ~(size_t)255; return pp; };
  float* h_f      = (float*)alloc(MN_SZ * 4);
  bf16*  h_bf     = (bf16*)alloc(MN_SZ * 2);
  float* h_mid    = (float*)alloc(MN_SZ * 4);
  bf16*  h_mid_bf = (bf16*)alloc(MN_SZ * 2);
  float* tmp      = (float*)alloc(MN_SZ * 4 * 4);   // split-K partials z=0..3
  float* h_base   = tmp + 3 * MN_SZ;                // dead after embedding; overlay
  float* p_buf    = (float*)alloc((size_t)N_TOK * 2 * 4);
  float* s_buf    = (float*)alloc((size_t)N_TOK * 4);
  bf16*  qkv      = (bf16*)alloc((size_t)N_TOK * 1536 * 2);
  bf16*  vt       = (bf16*)alloc(MN_SZ * 2);
  bf16*  ctx      = (bf16*)alloc(MN_SZ * 2);
  bf16*  a1       = (bf16*)alloc((size_t)N_TOK * F_SZ * 2);
  bf16*  wqkv_bf  = (bf16*)alloc((size_t)L_SZ * 2304 * 768 * 2);
  bf16*  wo_bf    = (bf16*)alloc((size_t)L_SZ * 768 * 768 * 2);
  bf16*  w1_bf    = (bf16*)alloc((size_t)L_SZ * 3072 * 768 * 2);
  bf16*  w2_bf    = (bf16*)alloc((size_t)L_SZ * 768 * 3072 * 2);
  (void)ws_size; (void)in_sizes; (void)n_in; (void)out_size;

  // weight conversion (every call; inputs restored each timed iteration)
  build_wqkv_kernel<<<(12 * 2304 * 768 / 4 + 255) / 256, 256, 0, stream>>>(Wq, Wk, Wv, wqkv_bf);
  f2b_kernel<<<(12 * 768 * 768 / 4 + 255) / 256, 256, 0, stream>>>(Wo, wo_bf, 12 * 768 * 768 / 4);
  f2b_kernel<<<(12 * 3072 * 768 / 4 + 255) / 256, 256, 0, stream>>>(W1, w1_bf, 12 * 3072 * 768 / 4);
  f2b_kernel<<<(12 * 768 * 3072 / 4 + 255) / 256, 256, 0, stream>>>(W2, w2_bf, 12 * 768 * 3072 / 4);

  // embedding stage
  embed_a_kernel<<<N_TOK, 256, 0, stream>>>(input_ids, tok_emb, pos_emb, prototypes, log_tau,
                                            h_base, p_buf);
  embed_c_kernel<<<N_TOK, 256, 0, stream>>>(h_base, p_buf, lang_emb, switch_emb, emb_ln_w,
                                            emb_ln_b, s_buf, h_f, h_bf);

  for (int l = 0; l < 12; ++l) {
    gemm_nt<3><<<dim3(32, 18), 256, 0, stream>>>(h_bf, wqkv_bf + (size_t)l * 2304 * 768, qkv,
                                                 vt, nullptr, N_TOK, 2304, 768);
    attn_kernel<<<dim3(16, 12, 8), 256, 0, stream>>>(qkv, vt, p_buf, s_buf, attn_mask,
                                                     compat, gamma, l, ctx);
    gemm_nt<1><<<dim3(32, 6, 2), 256, 0, stream>>>(ctx, wo_bf + (size_t)l * 768 * 768, tmp,
                                                   nullptr, nullptr, N_TOK, 768, 768);
    ln5_kernel<2><<<N_TOK, 256, 0, stream>>>(h_f, tmp, Wo_b + l * 768,
                                             ln1_w + l * 768, ln1_b + l * 768, h_mid, h_mid_bf);
    gemm_nt<2><<<dim3(32, 24), 256, 0, stream>>>(h_mid_bf, w1_bf + (size_t)l * 3072 * 768, a1,
                                                 nullptr, b1 + l * 3072, N_TOK, 3072, 768);
    gemm_nt<1><<<dim3(32, 6, 4), 256, 0, stream>>>(a1, w2_bf + (size_t)l * 768 * 3072, tmp,
                                                   nullptr, nullptr, N_TOK, 768, 3072);
    float* hdst = (l == 11) ? (float*)d_out : h_f;
    ln5_kernel<4><<<N_TOK, 256, 0, stream>>>(h_mid, tmp, b2 + l * 768,
                                             ln2_w + l * 768, ln2_b + l * 768, hdst, h_bf);
  }
}

// Round 6
// 2776.162 us; speedup vs baseline: 1.0296x; 1.0082x over previous
//
#include <hip/hip_runtime.h>
#include <hip/hip_bf16.h>
#include <math.h>

// SBERTa forward, MI355X gfx950.
// B=8 T=512 D=768 L=12 H=12 F=3072 K=2 DH=64, N_tok=4096.
// GEMMs: bf16 MFMA 16x16x32, NT layout, 128x128 tile, BK=64 K-steps,
// global_load_lds width-16 staging, XOR-preswizzled source + swizzled ds_read.
// Wo split-K=2, W2 split-K=4.
// LN/embed: wave-per-row (64 lanes x 3 float4), shfl-only reduce, no barriers,
// grid 1024 (was 4096 one-row blocks with 2 syncthreads each).
// Weight conversion fused into one kernel (was 4 serialized launches).
// Attention: padded score LDS, softmax in regs, P bf16 in reused LDS.

typedef __bf16 bf16;
typedef __attribute__((ext_vector_type(8))) __bf16 bf16x8;
typedef __attribute__((ext_vector_type(4))) __bf16 bf16x4;
typedef __attribute__((ext_vector_type(4))) float f32x4;

#define N_TOK 4096
#define D_SZ 768
#define F_SZ 3072
#define L_SZ 12
#define MN_SZ ((size_t)N_TOK * D_SZ)
#define SPITCH 516  // f32 score pitch (pad 4 -> 2-way bank alias only, free)
#define PPITCH 520  // bf16 P pitch (spreads ds_read_b128 across bank groups)

// async global->LDS, 16B per lane, wave-uniform LDS base + lane*16
__device__ __forceinline__ void async_ld16(const void* g, void* l) {
  __builtin_amdgcn_global_load_lds((const __attribute__((address_space(1))) void*)g,
                                   (__attribute__((address_space(3))) void*)l, 16, 0, 0);
}

// ---------------------------------------------------------------- converts
// One kernel, three linear f2b regions + the wqkv interleave region.
__global__ void __launch_bounds__(256) convert_all_kernel(
    const float* __restrict__ Wq, const float* __restrict__ Wk, const float* __restrict__ Wv,
    const float* __restrict__ Wo, const float* __restrict__ W1, const float* __restrict__ W2,
    bf16* __restrict__ wqkv_bf, bf16* __restrict__ wo_bf,
    bf16* __restrict__ w1_bf, bf16* __restrict__ w2_bf) {
  const long nq = 12L * 2304 * 768 / 4;
  const long no = 12L * 768 * 768 / 4;
  const long n1 = 12L * 3072 * 768 / 4;
  long i = (long)blockIdx.x * 256 + threadIdx.x;
  const float* src;
  bf16* dst;
  if (i < nq) {
    // wqkv interleave: per layer rows 0..767=Wq, 768..1535=Wk, 1536..=Wv; ld 768
    long idx = i * 4;
    const long per_layer = 2304L * 768;
    int l = (int)(idx / per_layer);
    int rem = (int)(idx - (long)l * per_layer);
    int r = rem / 768;
    int c = rem - r * 768;
    if (r < 768)       src = Wq + ((size_t)l * 768 + r) * 768 + c;
    else if (r < 1536) src = Wk + ((size_t)l * 768 + (r - 768)) * 768 + c;
    else               src = Wv + ((size_t)l * 768 + (r - 1536)) * 768 + c;
    dst = wqkv_bf + idx;
  } else if (i < nq + no) {
    long c = i - nq;
    src = Wo + c * 4; dst = wo_bf + c * 4;
  } else if (i < nq + no + n1) {
    long c = i - nq - no;
    src = W1 + c * 4; dst = w1_bf + c * 4;
  } else if (i < nq + no + n1 + n1) {
    long c = i - nq - no - n1;
    src = W2 + c * 4; dst = w2_bf + c * 4;
  } else return;
  float4 v = *(const float4*)src;
  bf16x4 o; o.x = (bf16)v.x; o.y = (bf16)v.y; o.z = (bf16)v.z; o.w = (bf16)v.w;
  *(bf16x4*)dst = o;
}

// ---------------------------------------------------------------- wave reduce
__device__ __forceinline__ void wave_reduce2(float& a, float& b) {
  #pragma unroll
  for (int off = 32; off; off >>= 1) {
    a += __shfl_xor(a, off);
    b += __shfl_xor(b, off);
  }
}

// ---------------------------------------------------------------- embedding
// wave-per-row: block = 4 waves = 4 rows; 64 lanes x 3 float4 per row.
__global__ void __launch_bounds__(256) embed_a_kernel(const int* __restrict__ ids,
    const float* __restrict__ tok, const float* __restrict__ pos,
    const float* __restrict__ proto, const float* __restrict__ log_tau,
    float* __restrict__ h_base, float* __restrict__ p_out) {
  int n = blockIdx.x * 4 + (threadIdx.x >> 6);
  int lane = threadIdx.x & 63;
  int t = n & 511;
  int id = ids[n];
  float d0 = 0.f, d1 = 0.f;
  #pragma unroll
  for (int c = 0; c < 3; c++) {
    int j = c * 256 + lane * 4;
    float4 tv = *(const float4*)(tok + (size_t)id * 768 + j);
    float4 pv = *(const float4*)(pos + (size_t)t * 768 + j);
    float4 v; v.x = tv.x + pv.x; v.y = tv.y + pv.y; v.z = tv.z + pv.z; v.w = tv.w + pv.w;
    *(float4*)(h_base + (size_t)n * 768 + j) = v;
    float4 q0 = *(const float4*)(proto + j);
    float4 q1 = *(const float4*)(proto + 768 + j);
    d0 += v.x * q0.x + v.y * q0.y + v.z * q0.z + v.w * q0.w;
    d1 += v.x * q1.x + v.y * q1.y + v.z * q1.z + v.w * q1.w;
  }
  wave_reduce2(d0, d1);
  if (lane == 0) {
    float tau = fmaxf(__expf(log_tau[0]), 0.25f);
    float a = d0 / tau, bb = d1 / tau;
    float m = fmaxf(a, bb);
    float e0 = __expf(a - m), e1 = __expf(bb - m);
    float si = e0 + e1;
    p_out[n * 2] = e0 / si;
    p_out[n * 2 + 1] = e1 / si;
  }
}

__global__ void __launch_bounds__(256) embed_c_kernel(const float* __restrict__ h_base,
    const float* __restrict__ p, const float* __restrict__ lang, const float* __restrict__ sw,
    const float* __restrict__ lw, const float* __restrict__ lb,
    float* __restrict__ s_out, float* __restrict__ h_out, bf16* __restrict__ h_bf) {
  int n = blockIdx.x * 4 + (threadIdx.x >> 6);
  int lane = threadIdx.x & 63;
  int t = n & 511;
  float p0 = p[n * 2], p1 = p[n * 2 + 1];
  float sv = 0.f;
  if (t > 0) sv = 1.f - (p0 * p[(n - 1) * 2] + p1 * p[(n - 1) * 2 + 1]);
  if (lane == 0) s_out[n] = sv;
  float4 x[3]; float sum = 0.f, sq = 0.f;
  #pragma unroll
  for (int c = 0; c < 3; c++) {
    int j = c * 256 + lane * 4;
    float4 hv = *(const float4*)(h_base + (size_t)n * 768 + j);
    float4 l0 = *(const float4*)(lang + j);
    float4 l1 = *(const float4*)(lang + 768 + j);
    float4 sv4 = *(const float4*)(sw + j);
    float4 v;
    v.x = hv.x + p0 * l0.x + p1 * l1.x + sv * sv4.x;
    v.y = hv.y + p0 * l0.y + p1 * l1.y + sv * sv4.y;
    v.z = hv.z + p0 * l0.z + p1 * l1.z + sv * sv4.z;
    v.w = hv.w + p0 * l0.w + p1 * l1.w + sv * sv4.w;
    x[c] = v;
    sum += v.x + v.y + v.z + v.w;
    sq += v.x * v.x + v.y * v.y + v.z * v.z + v.w * v.w;
  }
  wave_reduce2(sum, sq);
  float mean = sum * (1.f / 768.f);
  float var = fmaxf(sq * (1.f / 768.f) - mean * mean, 0.f);
  float inv = rsqrtf(var + 1e-12f);
  #pragma unroll
  for (int c = 0; c < 3; c++) {
    int j = c * 256 + lane * 4;
    float4 wv = *(const float4*)(lw + j);
    float4 bv4 = *(const float4*)(lb + j);
    float4 o;
    o.x = (x[c].x - mean) * inv * wv.x + bv4.x;
    o.y = (x[c].y - mean) * inv * wv.y + bv4.y;
    o.z = (x[c].z - mean) * inv * wv.z + bv4.z;
    o.w = (x[c].w - mean) * inv * wv.w + bv4.w;
    *(float4*)(h_out + (size_t)n * 768 + j) = o;
    bf16x4 ob; ob.x = (bf16)o.x; ob.y = (bf16)o.y; ob.z = (bf16)o.z; ob.w = (bf16)o.w;
    *(bf16x4*)(h_bf + (size_t)n * 768 + j) = ob;
  }
}

// ---------------------------------------------------------------- fused LN (residual + NZ partials)
// wave-per-row; out = LN(x1 + sum_z t[z] + bias) * w + bv ; writes fp32 + bf16
template <int NZ>
__global__ void __launch_bounds__(256) ln5_kernel(const float* __restrict__ x1,
    const float* __restrict__ t, const float* __restrict__ bias,
    const float* __restrict__ w, const float* __restrict__ bv,
    float* __restrict__ out_f, bf16* __restrict__ out_b) {
  int n = blockIdx.x * 4 + (threadIdx.x >> 6);
  int lane = threadIdx.x & 63;
  float4 x[3]; float sum = 0.f, sq = 0.f;
  #pragma unroll
  for (int c = 0; c < 3; c++) {
    int j = c * 256 + lane * 4;
    size_t o = (size_t)n * 768 + j;
    float4 v = *(const float4*)(x1 + o);
    float4 bb = *(const float4*)(bias + j);
    v.x += bb.x; v.y += bb.y; v.z += bb.z; v.w += bb.w;
    #pragma unroll
    for (int z = 0; z < NZ; z++) {
      float4 tz = *(const float4*)(t + o + (size_t)z * MN_SZ);
      v.x += tz.x; v.y += tz.y; v.z += tz.z; v.w += tz.w;
    }
    x[c] = v;
    sum += v.x + v.y + v.z + v.w;
    sq += v.x * v.x + v.y * v.y + v.z * v.z + v.w * v.w;
  }
  wave_reduce2(sum, sq);
  float mean = sum * (1.f / 768.f);
  float var = fmaxf(sq * (1.f / 768.f) - mean * mean, 0.f);
  float inv = rsqrtf(var + 1e-12f);
  #pragma unroll
  for (int c = 0; c < 3; c++) {
    int j = c * 256 + lane * 4;
    size_t o = (size_t)n * 768 + j;
    float4 wv = *(const float4*)(w + j);
    float4 bv4 = *(const float4*)(bv + j);
    float4 ov;
    ov.x = (x[c].x - mean) * inv * wv.x + bv4.x;
    ov.y = (x[c].y - mean) * inv * wv.y + bv4.y;
    ov.z = (x[c].z - mean) * inv * wv.z + bv4.z;
    ov.w = (x[c].w - mean) * inv * wv.w + bv4.w;
    *(float4*)(out_f + o) = ov;
    bf16x4 ob; ob.x = (bf16)ov.x; ob.y = (bf16)ov.y; ob.z = (bf16)ov.z; ob.w = (bf16)ov.w;
    *(bf16x4*)(out_b + o) = ob;
  }
}

// ---------------------------------------------------------------- GEMM (NT)
// C[m,n] = sum_k A[m,k]*B[n,k].  BK=64 K-steps; LDS [128][64] bf16 per operand,
// XOR-swizzled: LDS row r chunk c (16B units) holds global chunk c^(r&7).
// MODE 1: f32 out, split-K over blockIdx.z, out C + z*M*N.
// MODE 2: bias+gelu, bf16 out.
// MODE 3: QKV: cols <1536 -> bf16 C (ld 1536); cols >=1536 -> transposed into vt C2.
template <int MODE>
__global__ void __launch_bounds__(256) gemm_nt(const bf16* __restrict__ A,
    const bf16* __restrict__ B, void* __restrict__ C, bf16* __restrict__ C2,
    const float* __restrict__ bias, int M, int N, int K) {
  __shared__ __align__(16) bf16 As[128 * 64];
  __shared__ __align__(16) bf16 Bs[128 * 64];
  const int tid = threadIdx.x;
  const int lane = tid & 63;
  const int wave = tid >> 6;
  const int wm = wave >> 1, wn = wave & 1;
  const int m0 = blockIdx.x * 128, n0 = blockIdx.y * 128;
  const int fr = lane & 15, fq = lane >> 4;
  const int lrow = lane >> 3;                 // 0..7 : row within 8-row stage chunk
  const int lcol = ((lane & 7) ^ lrow) << 3;  // pre-swizzled global col (elems)
  const int xsw = (fr & 7) << 4;              // byte XOR for swizzled ds_read

  int kb = 0, ke = K;
  if (MODE == 1) { int ks = K / gridDim.z; kb = blockIdx.z * ks; ke = kb + ks; }

  f32x4 acc[4][4] = {};
  const bf16* Ap = A + (size_t)(m0 + wave * 8 + lrow) * K + lcol;
  const bf16* Bp = B + (size_t)(n0 + wave * 8 + lrow) * K + lcol;
  bf16* AsW = &As[wave * 8 * 64];
  bf16* BsW = &Bs[wave * 8 * 64];
  for (int k0 = kb; k0 < ke; k0 += 64) {
    #pragma unroll
    for (int c = 0; c < 4; c++) {
      async_ld16(Ap + (size_t)(c * 32) * K + k0, AsW + c * 32 * 64);
      async_ld16(Bp + (size_t)(c * 32) * K + k0, BsW + c * 32 * 64);
    }
    __syncthreads();
    #pragma unroll
    for (int kk = 0; kk < 2; kk++) {
      bf16x8 af[4], bfr[4];
      #pragma unroll
      for (int i = 0; i < 4; i++)
        af[i] = *(const bf16x8*)((const char*)As +
                 (wm * 64 + i * 16 + fr) * 128 + ((kk * 64 + fq * 16) ^ xsw));
      #pragma unroll
      for (int i = 0; i < 4; i++)
        bfr[i] = *(const bf16x8*)((const char*)Bs +
                 (wn * 64 + i * 16 + fr) * 128 + ((kk * 64 + fq * 16) ^ xsw));
      #pragma unroll
      for (int i = 0; i < 4; i++)
        #pragma unroll
        for (int j = 0; j < 4; j++)
          acc[i][j] = __builtin_amdgcn_mfma_f32_16x16x32_bf16(af[i], bfr[j], acc[i][j], 0, 0, 0);
    }
    __syncthreads();
  }

  const bool vregion = (MODE == 3) && (n0 >= 1536);
  float* Cz = (MODE == 1) ? ((float*)C + (size_t)blockIdx.z * M * N) : (float*)C;
  #pragma unroll
  for (int i = 0; i < 4; i++) {
    int row0 = m0 + wm * 64 + i * 16 + fq * 4;
    #pragma unroll
    for (int j = 0; j < 4; j++) {
      int col = n0 + wn * 64 + j * 16 + fr;
      if (MODE == 3 && vregion) {
        int vcol = col - 1536;
        int h = vcol >> 6, dh = vcol & 63;
        int b = row0 >> 9, t0 = row0 & 511;
        bf16x4 o;
        #pragma unroll
        for (int r = 0; r < 4; r++) o[r] = (bf16)acc[i][j][r];
        *(bf16x4*)&C2[((size_t)(b * 12 + h) * 64 + dh) * 512 + t0] = o;
      } else {
        #pragma unroll
        for (int r = 0; r < 4; r++) {
          float v = acc[i][j][r];
          if (MODE == 2) {
            v += bias[col];
            v = 0.5f * v * (1.f + erff(v * 0.70710678118654752f));
          }
          if (MODE == 1)      Cz[(size_t)(row0 + r) * N + col] = v;
          else if (MODE == 3) ((bf16*)C)[(size_t)(row0 + r) * 1536 + col] = (bf16)v;
          else                ((bf16*)C)[(size_t)(row0 + r) * N + col] = (bf16)v;
        }
      }
    }
  }
}

// ---------------------------------------------------------------- attention
// One block = (b, h, 32 q-rows). qkv ld = 1536 (Q cols 0..767, K cols 768..1535).
__global__ void __launch_bounds__(256) attn_kernel(const bf16* __restrict__ qkv,
    const bf16* __restrict__ vt, const float* __restrict__ p, const float* __restrict__ s,
    const int* __restrict__ mask, const float* __restrict__ compat,
    const float* __restrict__ gamma, int l, bf16* __restrict__ ctx) {
  __shared__ float scb[32 * SPITCH];  // 66048 B; reused as bf16[32*PPITCH] after softmax
  const int tid = threadIdx.x;
  const int lane = tid & 63;
  const int w = tid >> 6;
  const int fr = lane & 15, fq = lane >> 4;
  const int qc = blockIdx.x, h = blockIdx.y, b = blockIdx.z;
  const int i0 = qc * 32;
  const float* Cm = compat + (size_t)(l * 12 + h) * 4;  // 2x2 row-major [k][j]
  const float gl = gamma[l];

  // ---- phase 1: scores -> scb (fp32, pitch 516)
  bf16x8 qf[2][2];
  #pragma unroll
  for (int mt = 0; mt < 2; mt++)
    #pragma unroll
    for (int kk = 0; kk < 2; kk++)
      qf[mt][kk] = *(const bf16x8*)&qkv[(size_t)(b * 512 + i0 + mt * 16 + fr) * 1536 + h * 64 + kk * 32 + fq * 8];
  for (int ntl = 0; ntl < 8; ++ntl) {
    int j0 = (w * 8 + ntl) * 16;
    bf16x8 kf0 = *(const bf16x8*)&qkv[(size_t)(b * 512 + j0 + fr) * 1536 + 768 + h * 64 + fq * 8];
    bf16x8 kf1 = *(const bf16x8*)&qkv[(size_t)(b * 512 + j0 + fr) * 1536 + 768 + h * 64 + 32 + fq * 8];
    #pragma unroll
    for (int mt = 0; mt < 2; mt++) {
      f32x4 acc = {};
      acc = __builtin_amdgcn_mfma_f32_16x16x32_bf16(qf[mt][0], kf0, acc, 0, 0, 0);
      acc = __builtin_amdgcn_mfma_f32_16x16x32_bf16(qf[mt][1], kf1, acc, 0, 0, 0);
      #pragma unroll
      for (int r = 0; r < 4; r++)
        scb[(mt * 16 + fq * 4 + r) * SPITCH + j0 + fr] = acc[r] * 0.125f;
    }
  }

  // per-lane column-bias cache (cols j = lane + jj*64), loaded once
  float pj0[8], pj1[8], basej[8];
  #pragma unroll
  for (int jj = 0; jj < 8; jj++) {
    int j = lane + jj * 64;
    pj0[jj] = p[(b * 512 + j) * 2];
    pj1[jj] = p[(b * 512 + j) * 2 + 1];
    basej[jj] = gl * s[b * 512 + j] + (1.f - (float)mask[b * 512 + j]) * -10000.f;
  }
  __syncthreads();

  // ---- phase 2: softmax rows held in registers (8 rows/wave, 8 cols/lane)
  float xs[8][8];
  #pragma unroll
  for (int il = 0; il < 8; ++il) {
    int i = w * 8 + il;
    int qi = i0 + i;
    float p0 = p[(b * 512 + qi) * 2], p1 = p[(b * 512 + qi) * 2 + 1];
    float cp0 = p0 * Cm[0] + p1 * Cm[2];
    float cp1 = p0 * Cm[1] + p1 * Cm[3];
    float mx = -3.0e38f;
    #pragma unroll
    for (int jj = 0; jj < 8; jj++) {
      float v = scb[i * SPITCH + lane + jj * 64] + cp0 * pj0[jj] + cp1 * pj1[jj] + basej[jj];
      xs[il][jj] = v; mx = fmaxf(mx, v);
    }
    #pragma unroll
    for (int off = 32; off; off >>= 1) mx = fmaxf(mx, __shfl_xor(mx, off));
    float sum = 0.f;
    #pragma unroll
    for (int jj = 0; jj < 8; jj++) { float e = __expf(xs[il][jj] - mx); xs[il][jj] = e; sum += e; }
    #pragma unroll
    for (int off = 32; off; off >>= 1) sum += __shfl_xor(sum, off);
    float inv = 1.f / sum;
    #pragma unroll
    for (int jj = 0; jj < 8; jj++) xs[il][jj] *= inv;
  }
  __syncthreads();  // all reads of scb(f32) done -> safe to overwrite as bf16

  bf16* pbf = (bf16*)scb;
  #pragma unroll
  for (int il = 0; il < 8; ++il)
    #pragma unroll
    for (int jj = 0; jj < 8; jj++)
      pbf[(w * 8 + il) * PPITCH + lane + jj * 64] = (bf16)xs[il][jj];
  __syncthreads();

  // ---- phase 3: ctx = P V, P fragments via ds_read_b128
  const int mt3 = w & 1;
  const int ntb = (w >> 1) * 2;
  f32x4 acc3[2] = {};
  for (int kt = 0; kt < 16; ++kt) {
    bf16x8 af = *(const bf16x8*)&pbf[(mt3 * 16 + fr) * PPITCH + kt * 32 + fq * 8];
    #pragma unroll
    for (int np = 0; np < 2; np++) {
      bf16x8 vf = *(const bf16x8*)&vt[(size_t)((b * 12 + h) * 64 + (ntb + np) * 16 + fr) * 512 + kt * 32 + fq * 8];
      acc3[np] = __builtin_amdgcn_mfma_f32_16x16x32_bf16(af, vf, acc3[np], 0, 0, 0);
    }
  }
  #pragma unroll
  for (int np = 0; np < 2; np++)
    #pragma unroll
    for (int r = 0; r < 4; r++)
      ctx[(size_t)(b * 512 + i0 + mt3 * 16 + fq * 4 + r) * 768 + h * 64 + (ntb + np) * 16 + fr] = (bf16)acc3[np][r];
}

// ---------------------------------------------------------------- launcher
extern "C" void kernel_launch(void* const* d_in, const int* in_sizes, int n_in,
                              void* d_out, int out_size, void* d_ws, size_t ws_size,
                              hipStream_t stream) {
  const int*   input_ids  = (const int*)d_in[0];
  const int*   attn_mask  = (const int*)d_in[1];
  const float* tok_emb    = (const float*)d_in[2];
  const float* pos_emb    = (const float*)d_in[3];
  const float* lang_emb   = (const float*)d_in[4];
  const float* switch_emb = (const float*)d_in[5];
  const float* prototypes = (const float*)d_in[6];
  const float* log_tau    = (const float*)d_in[7];
  const float* emb_ln_w   = (const float*)d_in[8];
  const float* emb_ln_b   = (const float*)d_in[9];
  const float* Wq   = (const float*)d_in[10];
  const float* Wk   = (const float*)d_in[11];
  const float* Wv   = (const float*)d_in[12];
  const float* Wo   = (const float*)d_in[13];
  const float* Wo_b = (const float*)d_in[14];
  const float* compat = (const float*)d_in[15];
  const float* gamma  = (const float*)d_in[16];
  const float* W1   = (const float*)d_in[17];
  const float* b1   = (const float*)d_in[18];
  const float* W2   = (const float*)d_in[19];
  const float* b2   = (const float*)d_in[20];
  const float* ln1_w = (const float*)d_in[21];
  const float* ln1_b = (const float*)d_in[22];
  const float* ln2_w = (const float*)d_in[23];
  const float* ln2_b = (const float*)d_in[24];

  char* wsp = (char*)d_ws;
  size_t off = 0;
  auto alloc = [&](size_t bytes) { void* pp = wsp + off; off += (bytes + 255) & ~(size_t)255; return pp; };
  float* h_f      = (float*)alloc(MN_SZ * 4);
  bf16*  h_bf     = (bf16*)alloc(MN_SZ * 2);
  float* h_mid    = (float*)alloc(MN_SZ * 4);
  bf16*  h_mid_bf = (bf16*)alloc(MN_SZ * 2);
  float* tmp      = (float*)alloc(MN_SZ * 4 * 4);   // split-K partials z=0..3
  float* h_base   = tmp + 3 * MN_SZ;                // dead after embedding; overlay
  float* p_buf    = (float*)alloc((size_t)N_TOK * 2 * 4);
  float* s_buf    = (float*)alloc((size_t)N_TOK * 4);
  bf16*  qkv      = (bf16*)alloc((size_t)N_TOK * 1536 * 2);
  bf16*  vt       = (bf16*)alloc(MN_SZ * 2);
  bf16*  ctx      = (bf16*)alloc(MN_SZ * 2);
  bf16*  a1       = (bf16*)alloc((size_t)N_TOK * F_SZ * 2);
  bf16*  wqkv_bf  = (bf16*)alloc((size_t)L_SZ * 2304 * 768 * 2);
  bf16*  wo_bf    = (bf16*)alloc((size_t)L_SZ * 768 * 768 * 2);
  bf16*  w1_bf    = (bf16*)alloc((size_t)L_SZ * 3072 * 768 * 2);
  bf16*  w2_bf    = (bf16*)alloc((size_t)L_SZ * 768 * 3072 * 2);
  (void)ws_size; (void)in_sizes; (void)n_in; (void)out_size;

  // fused weight conversion (21,233,664 float4 chunks total)
  convert_all_kernel<<<82944, 256, 0, stream>>>(Wq, Wk, Wv, Wo, W1, W2,
                                                wqkv_bf, wo_bf, w1_bf, w2_bf);

  // embedding stage (wave-per-row, 1024 blocks)
  embed_a_kernel<<<N_TOK / 4, 256, 0, stream>>>(input_ids, tok_emb, pos_emb, prototypes,
                                                log_tau, h_base, p_buf);
  embed_c_kernel<<<N_TOK / 4, 256, 0, stream>>>(h_base, p_buf, lang_emb, switch_emb, emb_ln_w,
                                                emb_ln_b, s_buf, h_f, h_bf);

  for (int l = 0; l < 12; ++l) {
    gemm_nt<3><<<dim3(32, 18), 256, 0, stream>>>(h_bf, wqkv_bf + (size_t)l * 2304 * 768, qkv,
                                                 vt, nullptr, N_TOK, 2304, 768);
    attn_kernel<<<dim3(16, 12, 8), 256, 0, stream>>>(qkv, vt, p_buf, s_buf, attn_mask,
                                                     compat, gamma, l, ctx);
    gemm_nt<1><<<dim3(32, 6, 2), 256, 0, stream>>>(ctx, wo_bf + (size_t)l * 768 * 768, tmp,
                                                   nullptr, nullptr, N_TOK, 768, 768);
    ln5_kernel<2><<<N_TOK / 4, 256, 0, stream>>>(h_f, tmp, Wo_b + l * 768,
                                                 ln1_w + l * 768, ln1_b + l * 768, h_mid, h_mid_bf);
    gemm_nt<2><<<dim3(32, 24), 256, 0, stream>>>(h_mid_bf, w1_bf + (size_t)l * 3072 * 768, a1,
                                                 nullptr, b1 + l * 3072, N_TOK, 3072, 768);
    gemm_nt<1><<<dim3(32, 6, 4), 256, 0, stream>>>(a1, w2_bf + (size_t)l * 768 * 3072, tmp,
                                                   nullptr, nullptr, N_TOK, 768, 3072);
    float* hdst = (l == 11) ? (float*)d_out : h_f;
    ln5_kernel<4><<<N_TOK / 4, 256, 0, stream>>>(h_mid, tmp, b2 + l * 768,
                                                 ln2_w + l * 768, ln2_b + l * 768, hdst, h_bf);
  }
}